// Round 9
// baseline (181.339 us; speedup 1.0000x reference)
//
#include <hip/hip_runtime.h>

// Problem: B=64, K=17, H=128, W=128, RATIO=0.25, SIGMA=2.0
constexpr int   HW     = 16384;
constexpr int   NSLICE = 1088;          // 64*17
constexpr int   GTMAX  = 4096;          // pxl_num; kthvalue rank 12288 from bottom
constexpr float LO0    = 0.735f;        // static bracket around 0.75-quantile of U(0,1)
constexpr float HI0    = 0.770f;        // runtime-validated; exact fallback otherwise
constexpr int   CAP    = 1280;          // per-slice window capacity (mean ~574, +18 sigma)
constexpr int   BINS   = 1024;          // counting-refinement buckets
constexpr float BSCALE = (float)BINS / (HI0 - LO0);

constexpr int NTA = 256;                // kernel A threads (4 waves)
constexpr int V4A = 16;                 // float4 per thread (whole slice)
constexpr int NT3 = 256;                // MSE threads
constexpr int V43 = 4;                  // MSE float4 per thread per array
constexpr int NPART = NSLICE * 4;       // 4352

__device__ __forceinline__ int bucket_of(float x) {
    int b = (int)((x - LO0) * BSCALE);  // monotone on (LO0, HI0]
    return b < 0 ? 0 : (b > BINS - 1 ? BINS - 1 : b);
}

// ---------------- Kernel A: two homogeneous streams + validated selection tail ----------------
__global__ __launch_bounds__(NTA) void kA_scan_select(
    const float* __restrict__ tgt,
    float* __restrict__ th_out, int* __restrict__ mi_out)
{
    __shared__ float wvals[CAP];         // 5 KB window values
    __shared__ int   hist[BINS];         // 4 KB
    __shared__ float redf[4];
    __shared__ int   redi[4], redh[4], wtot[4], wcnt[4];
    __shared__ float cands[64];
    __shared__ int   s_n, s_nc, s_bstar, s_above;
    __shared__ float s_th;

    const int t = threadIdx.x, lane = t & 63, wid = t >> 6;
    const int s = blockIdx.x;
    const float4* t4 = reinterpret_cast<const float4*>(tgt) + (size_t)s * (HW / 4);

    for (int i = t; i < BINS; i += NTA) hist[i] = 0;
    if (t == 0) { s_n = 0; s_nc = 0; }

    // ---- loop1: branch-free stream: max + first-idx + #(>HI0). No LDS, no branches. ----
    float m = -1.f; int mi_t = 0; int hic = 0;
    for (int j = 0; j < V4A; ++j) {
        float4 v = t4[j * NTA + t];
        const int base = (j * NTA + t) * 4;
        float a[4] = {v.x, v.y, v.z, v.w};
        #pragma unroll
        for (int c = 0; c < 4; ++c) {
            float x = a[c];
            bool g = x > m;                    // strict > keeps first (thread idx increasing)
            m    = g ? x : m;
            mi_t = g ? (base + c) : mi_t;
            hic += (x > HI0) ? 1 : 0;
        }
    }
    // block reduce: argmax (first-max tie rule) + hi-count (validated pattern)
    {
        float am = m; int ai = mi_t; int rh = hic;
        #pragma unroll
        for (int off = 32; off > 0; off >>= 1) {
            float ov = __shfl_down(am, off); int ai2 = __shfl_down(ai, off);
            int oh = __shfl_down(rh, off);
            if (ov > am || (ov == am && ai2 < ai)) { am = ov; ai = ai2; }
            rh += oh;
        }
        if (lane == 0) { redf[wid] = am; redi[wid] = ai; redh[wid] = rh; }
    }
    __syncthreads();   // B1: orders hist zero, s_n/s_nc, red arrays
    float mv = redf[0]; int mi = redi[0]; int hi0 = 0;
    #pragma unroll
    for (int w = 0; w < 4; ++w) {
        if (redf[w] > mv || (redf[w] == mv && redi[w] < mi)) { mv = redf[w]; mi = redi[w]; }
        hi0 += redh[w];
    }
    const int need = (GTMAX + 1) - hi0;    // rank-from-top within window

    // ---- loop2: rescan (L1/L2-warm): collect window values + histogram ----
    for (int j = 0; j < V4A; ++j) {
        float4 v = t4[j * NTA + t];
        float a[4] = {v.x, v.y, v.z, v.w};
        #pragma unroll
        for (int c = 0; c < 4; ++c) {
            float x = a[c];
            if (x > LO0 && x <= HI0) {
                int pos = atomicAdd(&s_n, 1);
                if (pos < CAP) wvals[pos] = x;
                atomicAdd(&hist[bucket_of(x)], 1);
            }
        }
    }
    __syncthreads();   // B2
    const int n_raw = s_n;
    const bool valid = (n_raw <= CAP) && (hi0 <= GTMAX) && (need <= n_raw);

    float th = 0.f;
    bool done = false;                   // block-uniform throughout
    if (valid) {
        const int n = n_raw;
        // suffix scan (from top bucket): thread t owns bins 4t..4t+3   [R2-validated]
        int h[4], lsum = 0;
        #pragma unroll
        for (int c = 0; c < 4; ++c) { h[c] = hist[4 * t + c]; lsum += h[c]; }
        int incl = lsum;
        #pragma unroll
        for (int off = 1; off < 64; off <<= 1) {
            int v = __shfl_down(incl, off);
            incl += (lane + off < 64) ? v : 0;
        }
        if (lane == 0) wtot[wid] = incl;
        __syncthreads();
        int suf = incl - lsum;
        #pragma unroll
        for (int w = 0; w < 4; ++w) suf += (w > wid) ? wtot[w] : 0;
        int running = suf;               // count in buckets strictly above 4t+3
        #pragma unroll
        for (int c = 3; c >= 0; --c) {
            if (running < need && need <= running + h[c]) { s_bstar = 4 * t + c; s_above = running; }
            running += h[c];
        }
        __syncthreads();
        const int bstar = s_bstar, above = s_above;
        const int cnum  = hist[bstar];   // block-uniform
        if (cnum <= 64) {
            for (int i = t; i < n; i += NTA) {
                float x = wvals[i];
                if (bucket_of(x) == bstar) { int pos = atomicAdd(&s_nc, 1); cands[pos] = x; }
            }
            __syncthreads();
            const int mm = s_nc;         // == cnum, usually 1-2
            for (int i = t; i < mm; i += NTA) {
                float ci = cands[i];
                int gt = 0, eq = 0;
                for (int j = 0; j < mm; ++j) {
                    float cj = cands[j];
                    gt += (cj > ci) ? 1 : 0; eq += (cj == ci) ? 1 : 0;
                }
                int gg = hi0 + above + gt;
                if (gg <= GTMAX && gg + eq >= GTMAX + 1) s_th = ci;
            }
            __syncthreads();
            th = s_th;
            done = true;
        }
    }
    if (!done) {
        // exact fallback (rare): value bisection re-reading this slice (cache-warm) [R2-validated]
        float lo = -1.0f, hiv = mv;
        int g_lo = HW, g_hiC = 0;
        bool degen = false;
        while (g_lo - g_hiC > 48) {
            float mid = 0.5f * (lo + hiv);
            if (!(mid > lo && mid < hiv)) { degen = true; break; }
            int cnt = 0;
            for (int j = 0; j < V4A; ++j) {
                float4 v = t4[j * NTA + t];
                cnt += (v.x > mid) + (v.y > mid) + (v.z > mid) + (v.w > mid);
            }
            #pragma unroll
            for (int off = 32; off > 0; off >>= 1) cnt += __shfl_down(cnt, off);
            if (lane == 0) wcnt[wid] = cnt;
            __syncthreads();
            int g = 0;
            #pragma unroll
            for (int w = 0; w < 4; ++w) g += wcnt[w];
            __syncthreads();
            if (g >= GTMAX + 1) { lo = mid; g_lo = g; }
            else                { hiv = mid; g_hiC = g; }
        }
        if (degen) th = hiv;
        else {
            if (t == 0) s_nc = 0;
            __syncthreads();
            for (int j = 0; j < V4A; ++j) {
                float4 v = t4[j * NTA + t];
                float a[4] = {v.x, v.y, v.z, v.w};
                for (int c = 0; c < 4; ++c) {
                    float x = a[c];
                    if (x > lo && x <= hiv) { int pos = atomicAdd(&s_nc, 1); if (pos < 64) cands[pos] = x; }
                }
            }
            __syncthreads();
            int mm = s_nc; mm = mm > 64 ? 64 : mm;
            for (int i = t; i < mm; i += NTA) {
                float ci = cands[i];
                int gt = 0, eq = 0;
                for (int j = 0; j < mm; ++j) {
                    float cj = cands[j];
                    gt += (cj > ci) ? 1 : 0; eq += (cj == ci) ? 1 : 0;
                }
                int gg = g_hiC + gt;
                if (gg <= GTMAX && gg + eq >= GTMAX + 1) s_th = ci;
            }
            __syncthreads();
            th = s_th;
        }
    }
    if (t == 0) { th_out[s] = th; mi_out[s] = mi; }
}

// ---------------- K3: pure streaming masked MSE (quarter-slice per block) [R3-validated] ----
// g = exp(-d2/8) only within the 31x31 box (outside g<=1.3e-14; error ~1e-11).
__global__ __launch_bounds__(NT3, 8) void k3_mse(
    const float* __restrict__ pred, const float* __restrict__ tgt,
    const float* __restrict__ th_in, const int* __restrict__ mi_in,
    float* __restrict__ part)
{
    __shared__ float redf[4];
    const int t = threadIdx.x, lane = t & 63, wid = t >> 6;
    const int bid = blockIdx.x;
    const int s = bid >> 2, q = bid & 3;
    const float th = th_in[s];
    const int mi = mi_in[s];
    const int cyi = mi >> 7, cxi = mi & 127;
    const float4* t4 = reinterpret_cast<const float4*>(tgt)  + (size_t)s * (HW / 4) + q * 1024;
    const float4* p4 = reinterpret_cast<const float4*>(pred) + (size_t)s * (HW / 4) + q * 1024;

    float4 tv[V43], pv[V43];
    #pragma unroll
    for (int j = 0; j < V43; ++j) { tv[j] = t4[j * NT3 + t]; pv[j] = p4[j * NT3 + t]; }

    float sum = 0.f;
    #pragma unroll
    for (int j = 0; j < V43; ++j) {
        const int base = (q * 1024 + j * NT3 + t) * 4;
        float at[4] = {tv[j].x, tv[j].y, tv[j].z, tv[j].w};
        float ap[4] = {pv[j].x, pv[j].y, pv[j].z, pv[j].w};
        #pragma unroll
        for (int c = 0; c < 4; ++c) {
            if (at[c] > th) {
                const int idx = base + c;
                const int dy = (idx >> 7) - cyi, dx = (idx & 127) - cxi;
                float p = ap[c];
                if (dy >= -15 && dy <= 15 && dx >= -15 && dx <= 15) {
                    float g = __expf((float)(dy * dy + dx * dx) * -0.125f);
                    float d = p - g;
                    sum += d * d;
                } else {
                    sum += p * p;
                }
            }
        }
    }
    #pragma unroll
    for (int off = 32; off > 0; off >>= 1) sum += __shfl_down(sum, off);
    if (lane == 0) redf[wid] = sum;
    __syncthreads();
    if (t == 0) part[bid] = (redf[0] + redf[1]) + (redf[2] + redf[3]);
}

// ---------------- K4: final reduce [R3-validated] ----------------
__global__ __launch_bounds__(256) void k4_final(
    const float* __restrict__ part, float* __restrict__ out)
{
    __shared__ float red[4];
    const int t = threadIdx.x;
    float s = 0.f;
    for (int i = t; i < NPART; i += 256) s += part[i];
    #pragma unroll
    for (int off = 32; off > 0; off >>= 1) s += __shfl_down(s, off);
    if ((t & 63) == 0) red[t >> 6] = s;
    __syncthreads();
    if (t == 0)
        out[0] = ((red[0] + red[1]) + (red[2] + red[3]))
                 * (1.0f / ((float)GTMAX * (float)NSLICE));   // / pxl_num / (B*K)
}

extern "C" void kernel_launch(void* const* d_in, const int* in_sizes, int n_in,
                              void* d_out, int out_size, void* d_ws, size_t ws_size,
                              hipStream_t stream)
{
    const float* pred = (const float*)d_in[0];   // "output" in reference
    const float* tgt  = (const float*)d_in[1];   // "target"
    float* out = (float*)d_out;

    // workspace layout (floats): [0,1088) th | [1088,2176) mi (int) | [2176,6528) partials
    float* th   = (float*)d_ws;
    int*   mi   = (int*)(th + NSLICE);
    float* part = (float*)(mi + NSLICE);

    kA_scan_select<<<NSLICE, NTA, 0, stream>>>(tgt, th, mi);
    k3_mse        <<<NPART,  NT3, 0, stream>>>(pred, tgt, th, mi, part);
    k4_final      <<<1,      256, 0, stream>>>(part, out);
}

// Round 11
// 173.493 us; speedup vs baseline: 1.0452x; 1.0452x over previous
//
#include <hip/hip_runtime.h>

// Problem: B=64, K=17, H=128, W=128, RATIO=0.25, SIGMA=2.0
// Decomposition (R8-validated): loss_slice = Sum p^2*[x>HI0]           (streamed, no threshold)
//                                          + Sum p^2*[th<x<=HI0]       (compacted window pairs)
//                                          + Sum_box (g^2-2pg)*[x>th]  (31x31 box fixup)
constexpr int   HW     = 16384;
constexpr int   NSLICE = 1088;          // 64*17
constexpr int   NQ     = NSLICE * 4;    // 4352 quarter-slices
constexpr int   GTMAX  = 4096;          // pxl_num; kthvalue rank 12288 from bottom
constexpr float LO0    = 0.735f;        // static bracket around 0.75-quantile of U(0,1)
constexpr float HI0    = 0.770f;        // runtime-validated; exact fallback otherwise
constexpr int   SLOTS  = 10;            // per-thread stash (quarter lambda=0.56)
constexpr int   SSTR   = 11;            // stash stride pad
constexpr int   BINS   = 1024;          // counting-refinement buckets
constexpr float BSCALE = (float)BINS / (HI0 - LO0);
constexpr int   QCAP   = 224;           // per-quarter window cap (mean 143, +6.8 sigma)

constexpr int NTA = 256;                // threads everywhere

struct WS {
    float qmv[NQ];                      // quarter max value
    int   qmi[NQ];                      // quarter argmax (slice-local idx, first-max rule)
    int   qhi[NQ];                      // #(x > HI0) per quarter
    int   qn[NQ];                       // stored pair count; -1 = overflow
    float part[NQ + NSLICE];            // k1 hi-sums + k2 window/box sums
    float win[(size_t)NQ * QCAP * 2];   // interleaved (x, p) pairs
};

__device__ __forceinline__ int bucket_of(float x) {
    int b = (int)((x - LO0) * BSCALE);  // monotone on (LO0, HI0]
    return b < 0 ? 0 : (b > BINS - 1 ? BINS - 1 : b);
}

// ---------------- k1: quarter-slice fused stream of tgt+pred ----------------
__global__ __launch_bounds__(NTA) void k1_scan(
    const float* __restrict__ tgt, const float* __restrict__ pred,
    WS* __restrict__ w)
{
    __shared__ float sval[NTA * SSTR];   // 11 KB window x
    __shared__ float spre[NTA * SSTR];   // 11 KB window p
    __shared__ float redf[4], redp[4];
    __shared__ int   redi[4], redh[4], redo[4], redw[4], wn[4];

    const int t = threadIdx.x, lane = t & 63, wid = t >> 6;
    const int b = blockIdx.x;            // quarter id: s = b>>2, q = b&3
    const float4* t4 = reinterpret_cast<const float4*>(tgt)
                     + (size_t)(b >> 2) * (HW / 4) + (b & 3) * (HW / 16);
    const float4* p4 = reinterpret_cast<const float4*>(pred)
                     + (size_t)(b >> 2) * (HW / 4) + (b & 3) * (HW / 16);
    const int sbase = t * SSTR;

    // all 8 loads issued up-front (MLP); ~7 blocks/CU provide TLP
    float4 tv[4], pv[4];
    #pragma unroll
    for (int j = 0; j < 4; ++j) { tv[j] = t4[j * NTA + t]; pv[j] = p4[j * NTA + t]; }

    float bmax = -1.f; int bmi = 0; int hic = 0, myn = 0; float hsum = 0.f;
    #pragma unroll
    for (int j = 0; j < 4; ++j) {
        const int base = (j * NTA + t) * 4;     // quarter-local idx, increasing per thread
        float at[4] = {tv[j].x, tv[j].y, tv[j].z, tv[j].w};
        float ap[4] = {pv[j].x, pv[j].y, pv[j].z, pv[j].w};
        #pragma unroll
        for (int c = 0; c < 4; ++c) {
            float x = at[c], p = ap[c];
            if (x > bmax) { bmax = x; bmi = base + c; }
            if (x > HI0)      { ++hic; hsum += p * p; }
            else if (x > LO0) {
                if (myn < SLOTS) { sval[sbase + myn] = x; spre[sbase + myn] = p; }
                ++myn;
            }
        }
    }
    const int mynv = myn > SLOTS ? SLOTS : myn;

    // wave reduce: argmax(first) + counts + hi-sum + overflow
    {
        float am = bmax, rp = hsum; int ai = bmi, rh = hic, rw = myn, ro = (myn > SLOTS);
        #pragma unroll
        for (int off = 32; off > 0; off >>= 1) {
            float ov = __shfl_down(am, off); int ai2 = __shfl_down(ai, off);
            float op = __shfl_down(rp, off);
            int o1 = __shfl_down(rh, off), o2 = __shfl_down(rw, off), o3 = __shfl_down(ro, off);
            if (ov > am || (ov == am && ai2 < ai)) { am = ov; ai = ai2; }
            rp += op; rh += o1; rw += o2; ro |= o3;
        }
        if (lane == 0) { redf[wid] = am; redi[wid] = ai; redh[wid] = rh;
                         redp[wid] = rp; redw[wid] = rw; redo[wid] = ro; }
    }
    // wave inclusive scan of stored counts -> compaction offsets
    int incl = mynv;
    #pragma unroll
    for (int off = 1; off < 64; off <<= 1) {
        int v = __shfl_up(incl, off);
        if (lane >= off) incl += v;
    }
    if (lane == 63) wn[wid] = incl;
    __syncthreads();
    int blk_excl = 0;
    #pragma unroll
    for (int wv = 0; wv < 4; ++wv) blk_excl += (wv < wid) ? wn[wv] : 0;
    const int off0 = blk_excl + (incl - mynv);
    float* dst = &w->win[(size_t)b * QCAP * 2];
    for (int k = 0; k < mynv; ++k) {
        if (off0 + k < QCAP) {
            dst[(off0 + k) * 2]     = sval[sbase + k];
            dst[(off0 + k) * 2 + 1] = spre[sbase + k];
        }
    }
    if (t == 0) {
        float mv = redf[0], hs = 0.f; int mi = redi[0], hh = 0, rw = 0, ro = 0;
        #pragma unroll
        for (int wv = 0; wv < 4; ++wv) {
            if (redf[wv] > mv || (redf[wv] == mv && redi[wv] < mi)) { mv = redf[wv]; mi = redi[wv]; }
            hh += redh[wv]; hs += redp[wv]; rw += redw[wv]; ro |= redo[wv];
        }
        w->qmv[b] = mv;
        w->qmi[b] = (b & 3) * (HW / 4) + mi;     // slice-local index
        w->qhi[b] = hh;
        w->qn[b]  = (ro || rw > QCAP) ? -1 : rw;
        w->part[b] = hs;                          // Sum p^2 [x>HI0] for this quarter
    }
}

// ---------------- k2: per-slice selection on compacted pairs + window + box ----------------
__global__ __launch_bounds__(NTA) void k2_select(
    const float* __restrict__ tgt, const float* __restrict__ pred,
    WS* __restrict__ w)
{
    __shared__ float sx[4 * QCAP], sp[4 * QCAP];   // 7 KB
    __shared__ int   hist[BINS];                   // 4 KB
    __shared__ int   wtot[4], wcnt[4];
    __shared__ float cands[64];
    __shared__ int   s_nc, s_bstar, s_above;
    __shared__ float s_th;
    __shared__ float redr[4];

    const int t = threadIdx.x, lane = t & 63, wid = t >> 6;
    const int s = blockIdx.x;
    const float*  ts = tgt  + (size_t)s * HW;
    const float*  ps = pred + (size_t)s * HW;
    const float4* t4 = reinterpret_cast<const float4*>(ts);
    const float4* p4 = reinterpret_cast<const float4*>(ps);

    for (int i = t; i < BINS; i += NTA) hist[i] = 0;
    if (t == 0) s_nc = 0;

    // merge quarter summaries (uniform reads)
    int qn4[4], hi0 = 0; bool anyneg = false;
    float mv = -1.f; int mi = 0;
    #pragma unroll
    for (int q = 0; q < 4; ++q) {
        qn4[q] = w->qn[4 * s + q];
        anyneg |= (qn4[q] < 0);
        hi0 += w->qhi[4 * s + q];
        float v = w->qmv[4 * s + q]; int ix = w->qmi[4 * s + q];
        if (v > mv || (v == mv && ix < mi)) { mv = v; mi = ix; }
    }
    int n = 0;
    #pragma unroll
    for (int q = 0; q < 4; ++q) n += (qn4[q] < 0 ? 0 : qn4[q]);
    const int  need  = (GTMAX + 1) - hi0;
    const bool valid = (!anyneg) && (hi0 <= GTMAX) && (need <= n);
    __syncthreads();   // B0: hist zeroed, s_nc ready

    float th = 0.f;
    bool done = false;                   // block-uniform throughout
    if (valid) {
        int base = 0;
        for (int q = 0; q < 4; ++q) {
            const float* src = &w->win[(size_t)(4 * s + q) * QCAP * 2];
            const int qq = qn4[q];
            for (int i = t; i < qq; i += NTA) {
                float x = src[i * 2], p = src[i * 2 + 1];
                sx[base + i] = x; sp[base + i] = p;
                atomicAdd(&hist[bucket_of(x)], 1);
            }
            base += qq;
        }
        __syncthreads();   // B1
        // suffix scan from top bucket: thread t owns bins 4t..4t+3   [R2-validated]
        int h[4], lsum = 0;
        #pragma unroll
        for (int c = 0; c < 4; ++c) { h[c] = hist[4 * t + c]; lsum += h[c]; }
        int incl = lsum;
        #pragma unroll
        for (int off = 1; off < 64; off <<= 1) {
            int v = __shfl_down(incl, off);
            incl += (lane + off < 64) ? v : 0;
        }
        if (lane == 0) wtot[wid] = incl;
        __syncthreads();   // B2
        int suf = incl - lsum;
        #pragma unroll
        for (int wv = 0; wv < 4; ++wv) suf += (wv > wid) ? wtot[wv] : 0;
        int running = suf;
        #pragma unroll
        for (int c = 3; c >= 0; --c) {
            if (running < need && need <= running + h[c]) { s_bstar = 4 * t + c; s_above = running; }
            running += h[c];
        }
        __syncthreads();   // B3
        const int bstar = s_bstar, above = s_above;
        const int cnum  = hist[bstar];
        if (cnum <= 64) {
            for (int i = t; i < n; i += NTA) {
                float x = sx[i];
                if (bucket_of(x) == bstar) { int pos = atomicAdd(&s_nc, 1); cands[pos] = x; }
            }
            __syncthreads();   // B4
            const int m = s_nc;
            for (int i = t; i < m; i += NTA) {
                float ci = cands[i];
                int gt = 0, eq = 0;
                for (int j = 0; j < m; ++j) {
                    float cj = cands[j];
                    gt += (cj > ci) ? 1 : 0; eq += (cj == ci) ? 1 : 0;
                }
                int gg = hi0 + above + gt;
                if (gg <= GTMAX && gg + eq >= GTMAX + 1) s_th = ci;
            }
            __syncthreads();   // B5
            th = s_th;
            done = true;
        }
    }
    const bool fb = !done;
    float acc = 0.f;
    if (fb) {
        // exact bisection fallback (~never) re-reading slice (L3-warm)  [R9-validated]
        float lo = -1.0f, hiv = mv;
        int g_lo = HW, g_hiC = 0;
        bool degen = false;
        while (g_lo - g_hiC > 48) {
            float mid = 0.5f * (lo + hiv);
            if (!(mid > lo && mid < hiv)) { degen = true; break; }
            int cnt = 0;
            for (int j = 0; j < 16; ++j) {
                float4 v = t4[j * NTA + t];
                cnt += (v.x > mid) + (v.y > mid) + (v.z > mid) + (v.w > mid);
            }
            #pragma unroll
            for (int off = 32; off > 0; off >>= 1) cnt += __shfl_down(cnt, off);
            if (lane == 0) wcnt[wid] = cnt;
            __syncthreads();
            int g = 0;
            #pragma unroll
            for (int wv = 0; wv < 4; ++wv) g += wcnt[wv];
            __syncthreads();
            if (g >= GTMAX + 1) { lo = mid; g_lo = g; }
            else                { hiv = mid; g_hiC = g; }
        }
        if (degen) th = hiv;
        else {
            if (t == 0) s_nc = 0;
            __syncthreads();
            for (int j = 0; j < 16; ++j) {
                float4 v = t4[j * NTA + t];
                float a[4] = {v.x, v.y, v.z, v.w};
                for (int c = 0; c < 4; ++c) {
                    float x = a[c];
                    if (x > lo && x <= hiv) { int pos = atomicAdd(&s_nc, 1); if (pos < 64) cands[pos] = x; }
                }
            }
            __syncthreads();
            int m = s_nc; m = m > 64 ? 64 : m;
            for (int i = t; i < m; i += NTA) {
                float ci = cands[i];
                int gt = 0, eq = 0;
                for (int j = 0; j < m; ++j) {
                    float cj = cands[j];
                    gt += (cj > ci) ? 1 : 0; eq += (cj == ci) ? 1 : 0;
                }
                int gg = g_hiC + gt;
                if (gg <= GTMAX && gg + eq >= GTMAX + 1) s_th = ci;
            }
            __syncthreads();
            th = s_th;
        }
        // correction: p^2*([x>th] - [x>HI0]) over the slice (exact, L3-warm)
        for (int j = 0; j < 16; ++j) {
            float4 v  = t4[j * NTA + t];
            float4 pv = p4[j * NTA + t];
            float a[4]  = {v.x, v.y, v.z, v.w};
            float ap[4] = {pv.x, pv.y, pv.z, pv.w};
            for (int c = 0; c < 4; ++c) {
                float pp = ap[c] * ap[c];
                if (a[c] > th)  acc += pp;
                if (a[c] > HI0) acc -= pp;
            }
        }
    } else {
        // window contribution from compacted pairs
        for (int i = t; i < n; i += NTA)
            if (sx[i] > th) acc += sp[i] * sp[i];
    }

    // box fixup: (g^2 - 2pg) for masked elements in the 31x31 box around argmax.
    // Outside the box g<=1.3e-14 (error ~1e-11; same approx as all validated rounds).
    const int cyi = mi >> 7, cxi = mi & 127;
    for (int e = t; e < 961; e += NTA) {
        const int by = e / 31, bx = e - 31 * by;
        const int y = cyi - 15 + by, x = cxi - 15 + bx;
        if (y >= 0 && y < 128 && x >= 0 && x < 128) {
            const int idx = (y << 7) + x;
            float tg = ts[idx];
            if (tg > th) {
                float p = ps[idx];
                float d2 = (float)((by - 15) * (by - 15) + (bx - 15) * (bx - 15));
                float g = __expf(d2 * -0.125f);
                acc += g * (g - 2.0f * p);    // (p-g)^2 - p^2
            }
        }
    }

    #pragma unroll
    for (int off = 32; off > 0; off >>= 1) acc += __shfl_down(acc, off);
    if (lane == 0) redr[wid] = acc;
    __syncthreads();
    if (t == 0)
        w->part[NQ + s] = (redr[0] + redr[1]) + (redr[2] + redr[3]);
}

// ---------------- k3: final reduce over NQ + NSLICE partials ----------------
__global__ __launch_bounds__(256) void k3_final_fast(
    const WS* __restrict__ w, float* __restrict__ out)
{
    __shared__ float red[4];
    const int t = threadIdx.x;
    float s = 0.f;
    for (int i = t; i < NQ + NSLICE; i += 256) s += w->part[i];
    #pragma unroll
    for (int off = 32; off > 0; off >>= 1) s += __shfl_down(s, off);
    if ((t & 63) == 0) red[t >> 6] = s;
    __syncthreads();
    if (t == 0)
        out[0] = ((red[0] + red[1]) + (red[2] + red[3]))
                 * (1.0f / ((float)GTMAX * (float)NSLICE));   // / pxl_num / (B*K)
}

// ================= fallback path (small ws): R9 kernels, validated =================
constexpr int CAPF = 1280;
constexpr int V4A  = 16;
constexpr int NPART = NSLICE * 4;

__global__ __launch_bounds__(NTA) void kA_scan_select(
    const float* __restrict__ tgt,
    float* __restrict__ th_out, int* __restrict__ mi_out)
{
    __shared__ float wvals[CAPF];
    __shared__ int   hist[BINS];
    __shared__ float redf[4];
    __shared__ int   redi[4], redh[4], wtot[4], wcnt[4];
    __shared__ float cands[64];
    __shared__ int   s_n, s_nc, s_bstar, s_above;
    __shared__ float s_th;

    const int t = threadIdx.x, lane = t & 63, wid = t >> 6;
    const int s = blockIdx.x;
    const float4* t4 = reinterpret_cast<const float4*>(tgt) + (size_t)s * (HW / 4);

    for (int i = t; i < BINS; i += NTA) hist[i] = 0;
    if (t == 0) { s_n = 0; s_nc = 0; }

    float m = -1.f; int mi_t = 0; int hic = 0;
    for (int j = 0; j < V4A; ++j) {
        float4 v = t4[j * NTA + t];
        const int base = (j * NTA + t) * 4;
        float a[4] = {v.x, v.y, v.z, v.w};
        #pragma unroll
        for (int c = 0; c < 4; ++c) {
            float x = a[c];
            bool g = x > m;
            m = g ? x : m; mi_t = g ? (base + c) : mi_t;
            hic += (x > HI0) ? 1 : 0;
        }
    }
    {
        float am = m; int ai = mi_t; int rh = hic;
        #pragma unroll
        for (int off = 32; off > 0; off >>= 1) {
            float ov = __shfl_down(am, off); int ai2 = __shfl_down(ai, off);
            int oh = __shfl_down(rh, off);
            if (ov > am || (ov == am && ai2 < ai)) { am = ov; ai = ai2; }
            rh += oh;
        }
        if (lane == 0) { redf[wid] = am; redi[wid] = ai; redh[wid] = rh; }
    }
    __syncthreads();
    float mv = redf[0]; int mi = redi[0]; int hi0 = 0;
    #pragma unroll
    for (int w = 0; w < 4; ++w) {
        if (redf[w] > mv || (redf[w] == mv && redi[w] < mi)) { mv = redf[w]; mi = redi[w]; }
        hi0 += redh[w];
    }
    const int need = (GTMAX + 1) - hi0;

    for (int j = 0; j < V4A; ++j) {
        float4 v = t4[j * NTA + t];
        float a[4] = {v.x, v.y, v.z, v.w};
        #pragma unroll
        for (int c = 0; c < 4; ++c) {
            float x = a[c];
            if (x > LO0 && x <= HI0) {
                int pos = atomicAdd(&s_n, 1);
                if (pos < CAPF) wvals[pos] = x;
                atomicAdd(&hist[bucket_of(x)], 1);
            }
        }
    }
    __syncthreads();
    const int n_raw = s_n;
    const bool valid = (n_raw <= CAPF) && (hi0 <= GTMAX) && (need <= n_raw);

    float th = 0.f;
    bool done = false;
    if (valid) {
        const int n = n_raw;
        int h[4], lsum = 0;
        #pragma unroll
        for (int c = 0; c < 4; ++c) { h[c] = hist[4 * t + c]; lsum += h[c]; }
        int incl = lsum;
        #pragma unroll
        for (int off = 1; off < 64; off <<= 1) {
            int v = __shfl_down(incl, off);
            incl += (lane + off < 64) ? v : 0;
        }
        if (lane == 0) wtot[wid] = incl;
        __syncthreads();
        int suf = incl - lsum;
        #pragma unroll
        for (int w = 0; w < 4; ++w) suf += (w > wid) ? wtot[w] : 0;
        int running = suf;
        #pragma unroll
        for (int c = 3; c >= 0; --c) {
            if (running < need && need <= running + h[c]) { s_bstar = 4 * t + c; s_above = running; }
            running += h[c];
        }
        __syncthreads();
        const int bstar = s_bstar, above = s_above;
        const int cnum  = hist[bstar];
        if (cnum <= 64) {
            for (int i = t; i < n; i += NTA) {
                float x = wvals[i];
                if (bucket_of(x) == bstar) { int pos = atomicAdd(&s_nc, 1); cands[pos] = x; }
            }
            __syncthreads();
            const int mm = s_nc;
            for (int i = t; i < mm; i += NTA) {
                float ci = cands[i];
                int gt = 0, eq = 0;
                for (int j = 0; j < mm; ++j) {
                    float cj = cands[j];
                    gt += (cj > ci) ? 1 : 0; eq += (cj == ci) ? 1 : 0;
                }
                int gg = hi0 + above + gt;
                if (gg <= GTMAX && gg + eq >= GTMAX + 1) s_th = ci;
            }
            __syncthreads();
            th = s_th;
            done = true;
        }
    }
    if (!done) {
        float lo = -1.0f, hiv = mv;
        int g_lo = HW, g_hiC = 0;
        bool degen = false;
        while (g_lo - g_hiC > 48) {
            float mid = 0.5f * (lo + hiv);
            if (!(mid > lo && mid < hiv)) { degen = true; break; }
            int cnt = 0;
            for (int j = 0; j < V4A; ++j) {
                float4 v = t4[j * NTA + t];
                cnt += (v.x > mid) + (v.y > mid) + (v.z > mid) + (v.w > mid);
            }
            #pragma unroll
            for (int off = 32; off > 0; off >>= 1) cnt += __shfl_down(cnt, off);
            if (lane == 0) wcnt[wid] = cnt;
            __syncthreads();
            int g = 0;
            #pragma unroll
            for (int w = 0; w < 4; ++w) g += wcnt[w];
            __syncthreads();
            if (g >= GTMAX + 1) { lo = mid; g_lo = g; }
            else                { hiv = mid; g_hiC = g; }
        }
        if (degen) th = hiv;
        else {
            if (t == 0) s_nc = 0;
            __syncthreads();
            for (int j = 0; j < V4A; ++j) {
                float4 v = t4[j * NTA + t];
                float a[4] = {v.x, v.y, v.z, v.w};
                for (int c = 0; c < 4; ++c) {
                    float x = a[c];
                    if (x > lo && x <= hiv) { int pos = atomicAdd(&s_nc, 1); if (pos < 64) cands[pos] = x; }
                }
            }
            __syncthreads();
            int mm = s_nc; mm = mm > 64 ? 64 : mm;
            for (int i = t; i < mm; i += NTA) {
                float ci = cands[i];
                int gt = 0, eq = 0;
                for (int j = 0; j < mm; ++j) {
                    float cj = cands[j];
                    gt += (cj > ci) ? 1 : 0; eq += (cj == ci) ? 1 : 0;
                }
                int gg = g_hiC + gt;
                if (gg <= GTMAX && gg + eq >= GTMAX + 1) s_th = ci;
            }
            __syncthreads();
            th = s_th;
        }
    }
    if (t == 0) { th_out[s] = th; mi_out[s] = mi; }
}

__global__ __launch_bounds__(NTA, 8) void k3_mse(
    const float* __restrict__ pred, const float* __restrict__ tgt,
    const float* __restrict__ th_in, const int* __restrict__ mi_in,
    float* __restrict__ part)
{
    __shared__ float redf[4];
    const int t = threadIdx.x, lane = t & 63, wid = t >> 6;
    const int bid = blockIdx.x;
    const int s = bid >> 2, q = bid & 3;
    const float th = th_in[s];
    const int mi = mi_in[s];
    const int cyi = mi >> 7, cxi = mi & 127;
    const float4* t4 = reinterpret_cast<const float4*>(tgt)  + (size_t)s * (HW / 4) + q * 1024;
    const float4* p4 = reinterpret_cast<const float4*>(pred) + (size_t)s * (HW / 4) + q * 1024;

    float4 tv[4], pv[4];
    #pragma unroll
    for (int j = 0; j < 4; ++j) { tv[j] = t4[j * NTA + t]; pv[j] = p4[j * NTA + t]; }

    float sum = 0.f;
    #pragma unroll
    for (int j = 0; j < 4; ++j) {
        const int base = (q * 1024 + j * NTA + t) * 4;
        float at[4] = {tv[j].x, tv[j].y, tv[j].z, tv[j].w};
        float ap[4] = {pv[j].x, pv[j].y, pv[j].z, pv[j].w};
        #pragma unroll
        for (int c = 0; c < 4; ++c) {
            if (at[c] > th) {
                const int idx = base + c;
                const int dy = (idx >> 7) - cyi, dx = (idx & 127) - cxi;
                float p = ap[c];
                if (dy >= -15 && dy <= 15 && dx >= -15 && dx <= 15) {
                    float g = __expf((float)(dy * dy + dx * dx) * -0.125f);
                    float d = p - g;
                    sum += d * d;
                } else {
                    sum += p * p;
                }
            }
        }
    }
    #pragma unroll
    for (int off = 32; off > 0; off >>= 1) sum += __shfl_down(sum, off);
    if (lane == 0) redf[wid] = sum;
    __syncthreads();
    if (t == 0) part[bid] = (redf[0] + redf[1]) + (redf[2] + redf[3]);
}

__global__ __launch_bounds__(256) void k4_final_small(
    const float* __restrict__ part, float* __restrict__ out)
{
    __shared__ float red[4];
    const int t = threadIdx.x;
    float s = 0.f;
    for (int i = t; i < NPART; i += 256) s += part[i];
    #pragma unroll
    for (int off = 32; off > 0; off >>= 1) s += __shfl_down(s, off);
    if ((t & 63) == 0) red[t >> 6] = s;
    __syncthreads();
    if (t == 0)
        out[0] = ((red[0] + red[1]) + (red[2] + red[3]))
                 * (1.0f / ((float)GTMAX * (float)NSLICE));
}

extern "C" void kernel_launch(void* const* d_in, const int* in_sizes, int n_in,
                              void* d_out, int out_size, void* d_ws, size_t ws_size,
                              hipStream_t stream)
{
    const float* pred = (const float*)d_in[0];   // "output" in reference
    const float* tgt  = (const float*)d_in[1];   // "target"
    float* out = (float*)d_out;

    if (ws_size >= sizeof(WS)) {
        WS* w = (WS*)d_ws;
        k1_scan      <<<NQ,     NTA, 0, stream>>>(tgt, pred, w);
        k2_select    <<<NSLICE, NTA, 0, stream>>>(tgt, pred, w);
        k3_final_fast<<<1,      256, 0, stream>>>(w, out);
    } else {
        // small-ws fallback: R9-validated path (26 KB)
        float* th   = (float*)d_ws;
        int*   mi   = (int*)(th + NSLICE);
        float* part = (float*)(mi + NSLICE);
        kA_scan_select<<<NSLICE, NTA, 0, stream>>>(tgt, th, mi);
        k3_mse        <<<NPART,  NTA, 0, stream>>>(pred, tgt, th, mi, part);
        k4_final_small<<<1,      256, 0, stream>>>(part, out);
    }
}